// Round 2
// baseline (153.876 us; speedup 1.0000x reference)
//
#include <hip/hip_runtime.h>
#include <stdint.h>

#define NROWS 8192
#define DIM 128
#define NCHUNK 64      // j-chunks (128 j each)
#define NIBLK 64       // i-blocks (128 rows each)
#define MARGIN 0.5f

typedef short short8 __attribute__((ext_vector_type(8)));   // 8 bf16 (4 VGPRs)
typedef float f32x4 __attribute__((ext_vector_type(4)));
typedef int   int4v __attribute__((ext_vector_type(4)));

static __device__ __forceinline__ unsigned short f2bf(float f) {
    union { float f; unsigned u; } x; x.f = f;
    unsigned u = x.u;
    return (unsigned short)((u + 0x7FFFu + ((u >> 16) & 1u)) >> 16);  // RNE
}

// ---------------------------------------------------------------------------
// prep: bf16 copy of embeds, c_j = sq_j + 512 (f32 exact).
// One wave per row; lane handles 2 dims.
// ---------------------------------------------------------------------------
__global__ __launch_bounds__(256) void prep(const float* __restrict__ emb,
                                            unsigned short* __restrict__ e16,
                                            float* __restrict__ cbuf) {
    const int lane = threadIdx.x & 63;
    const int row = blockIdx.x * 4 + (threadIdx.x >> 6);
    const float2 v = reinterpret_cast<const float2*>(emb + row * DIM)[lane];
    float sq = v.x * v.x + v.y * v.y;
#pragma unroll
    for (int m = 1; m < 64; m <<= 1) sq += __shfl_xor(sq, m, 64);
    const unsigned pack = ((unsigned)f2bf(v.y) << 16) | (unsigned)f2bf(v.x);
    *reinterpret_cast<unsigned*>(e16 + row * DIM + lane * 2) = pack;
    if (lane == 0) cbuf[row] = sq + 512.0f;
}

// ---------------------------------------------------------------------------
// mine: fused Gram-GEMM + batch-hard mining.
// Grid: 64 i-blocks (128 rows) x 64 j-chunks (128 cols) = 4096 blocks.
// Block: 4 waves; wave owns 2 i-tiles of 16, iterates 8 j-tiles.
// MFMA D[m=j][n=i]; accumulator initialized with -c_j/2 so the final value is
// s = dot - c_j/2 = -(c_j - 2 dot)/2  (strictly negative).
//   hardest positive = max d2  -> most negative s -> MAX u32 bits
//   hardest negative = min d2  -> least negative s -> MIN u32 bits
// Candidate = (s_bits & ~8191) | j  (one v_bfi); sentinels 0 / 0xFFFFFFFF.
// ---------------------------------------------------------------------------
__global__ __launch_bounds__(256) void mine(const unsigned short* __restrict__ e16,
                                            const float* __restrict__ cbuf,
                                            const int* __restrict__ labels,
                                            unsigned* __restrict__ pos_part,
                                            unsigned* __restrict__ neg_part) {
    const int tid  = threadIdx.x;
    const int wave = tid >> 6;
    const int lane = tid & 63;
    const int l15  = lane & 15;
    const int lhi  = lane >> 4;
    const int iblk = blockIdx.x & (NIBLK - 1);
    const int cblk = blockIdx.x >> 6;
    const int ibase = iblk * 128 + wave * 32;

    // B operand (i side): held in registers for the whole kernel.
    short8 bfrag[2][4];
    int labi[2];
#pragma unroll
    for (int it = 0; it < 2; ++it) {
        const int row = ibase + it * 16 + l15;
#pragma unroll
        for (int ks = 0; ks < 4; ++ks)
            bfrag[it][ks] = *reinterpret_cast<const short8*>(e16 + row * DIM + ks * 32 + lhi * 8);
        labi[it] = labels[row];
    }

    unsigned bp[2] = {0u, 0u};
    unsigned bn[2] = {0xFFFFFFFFu, 0xFFFFFFFFu};

    const int jcbase = cblk * 128;
#pragma unroll 2
    for (int t = 0; t < 8; ++t) {
        const int jb = jcbase + t * 16;
        short8 af[4];
#pragma unroll
        for (int ks = 0; ks < 4; ++ks)
            af[ks] = *reinterpret_cast<const short8*>(e16 + (jb + l15) * DIM + ks * 32 + lhi * 8);
        const int4v labj = *reinterpret_cast<const int4v*>(labels + jb + lhi * 4);
        const f32x4 c4   = *reinterpret_cast<const f32x4*>(cbuf + jb + lhi * 4);
        const f32x4 cinit = c4 * -0.5f;

        f32x4 acc[2];
#pragma unroll
        for (int it = 0; it < 2; ++it)
            acc[it] = __builtin_amdgcn_mfma_f32_16x16x32_bf16(af[0], bfrag[it][0], cinit, 0, 0, 0);
#pragma unroll
        for (int ks = 1; ks < 4; ++ks)
#pragma unroll
            for (int it = 0; it < 2; ++it)
                acc[it] = __builtin_amdgcn_mfma_f32_16x16x32_bf16(af[ks], bfrag[it][ks], acc[it], 0, 0, 0);

        const int j0 = jb + lhi * 4;             // this lane's 4 j's: j0..j0+3
#pragma unroll
        for (int it = 0; it < 2; ++it) {
#pragma unroll
            for (int r = 0; r < 4; ++r) {
                union { float f; unsigned u; } cv; cv.f = acc[it][r];
                const unsigned cand = (cv.u & 0xFFFFE000u) | ((unsigned)(j0 + r) & 0x1FFFu);
                const bool eq = (labj[r] == labi[it]);
                const unsigned psel = eq ? cand : 0u;
                const unsigned nsel = eq ? 0xFFFFFFFFu : cand;
                bp[it] = bp[it] > psel ? bp[it] : psel;
                bn[it] = bn[it] < nsel ? bn[it] : nsel;
            }
        }
    }

    // cross-lane: lanes {l, l^16, l^32, l^48} share the same i
#pragma unroll
    for (int it = 0; it < 2; ++it) {
        unsigned p = bp[it], n = bn[it];
        unsigned o;
        o = (unsigned)__shfl_xor((int)p, 16, 64); p = p > o ? p : o;
        o = (unsigned)__shfl_xor((int)p, 32, 64); p = p > o ? p : o;
        o = (unsigned)__shfl_xor((int)n, 16, 64); n = n < o ? n : o;
        o = (unsigned)__shfl_xor((int)n, 32, 64); n = n < o ? n : o;
        if (lane < 16) {
            pos_part[cblk * NROWS + ibase + it * 16 + lane] = p;
            neg_part[cblk * NROWS + ibase + it * 16 + lane] = n;
        }
    }
}

// ---------------------------------------------------------------------------
// lossk: one row per wave. lane <-> chunk (64 chunks), full 64-lane butterfly,
// exact f32 ap/an from the mined indices, block sum -> bsum (no atomics).
// ---------------------------------------------------------------------------
__global__ __launch_bounds__(256) void lossk(const float* __restrict__ emb,
                                             const unsigned* __restrict__ pos_part,
                                             const unsigned* __restrict__ neg_part,
                                             float* __restrict__ bsum) {
    __shared__ float wsum[4];
    const int tid = threadIdx.x, lane = tid & 63, wave = tid >> 6;
    const int i = blockIdx.x * 4 + wave;          // 0..8191
    unsigned p = pos_part[lane * NROWS + i];
    unsigned n = neg_part[lane * NROWS + i];
#pragma unroll
    for (int m = 1; m < 64; m <<= 1) {
        unsigned o;
        o = (unsigned)__shfl_xor((int)p, m, 64); p = p > o ? p : o;
        o = (unsigned)__shfl_xor((int)n, m, 64); n = n < o ? n : o;
    }
    const int jp = (int)(p & 8191u);
    const int jn = (int)(n & 8191u);
    const float2 a = reinterpret_cast<const float2*>(emb + i  * DIM)[lane];
    const float2 b = reinterpret_cast<const float2*>(emb + jp * DIM)[lane];
    const float2 c = reinterpret_cast<const float2*>(emb + jn * DIM)[lane];
    float dx = a.x - b.x, dy = a.y - b.y;
    const float ap = dx * dx + dy * dy;
    dx = a.x - c.x; dy = a.y - c.y;
    const float an = dx * dx + dy * dy;
    float v = ap - an;
#pragma unroll
    for (int m = 1; m < 64; m <<= 1) v += __shfl_xor(v, m, 64);
    if (lane == 0) wsum[wave] = fmaxf(v + MARGIN, 0.f);
    __syncthreads();
    if (tid == 0) bsum[blockIdx.x] = wsum[0] + wsum[1] + wsum[2] + wsum[3];
}

// ---------------------------------------------------------------------------
// fin: reduce 2048 block sums -> mean. One block.
// ---------------------------------------------------------------------------
__global__ __launch_bounds__(256) void fin(const float* __restrict__ bsum,
                                           float* __restrict__ out) {
    __shared__ float wsum[4];
    const int tid = threadIdx.x, lane = tid & 63, wave = tid >> 6;
    float s = 0.f;
#pragma unroll
    for (int k = 0; k < 8; ++k) s += bsum[tid + k * 256];
#pragma unroll
    for (int m = 1; m < 64; m <<= 1) s += __shfl_xor(s, m, 64);
    if (lane == 0) wsum[wave] = s;
    __syncthreads();
    if (tid == 0) out[0] = (wsum[0] + wsum[1] + wsum[2] + wsum[3]) * (1.0f / (float)NROWS);
}

// ---------------------------------------------------------------------------
extern "C" void kernel_launch(void* const* d_in, const int* in_sizes, int n_in,
                              void* d_out, int out_size, void* d_ws, size_t ws_size,
                              hipStream_t stream) {
    const float* emb   = (const float*)d_in[0];
    const int* labels  = (const int*)d_in[1];
    float* out = (float*)d_out;
    char* ws = (char*)d_ws;

    unsigned short* e16 = (unsigned short*)ws;                       // 2 MB
    float* cbuf         = (float*)(ws + (size_t)2097152);            // 32 KB
    unsigned* pos_part  = (unsigned*)(ws + (size_t)2097152 + 32768); // 2 MB
    unsigned* neg_part  = pos_part + (size_t)NCHUNK * NROWS;         // 2 MB
    float* bsum         = (float*)(neg_part + (size_t)NCHUNK * NROWS); // 8 KB

    prep<<<2048, 256, 0, stream>>>(emb, e16, cbuf);
    mine<<<4096, 256, 0, stream>>>(e16, cbuf, labels, pos_part, neg_part);
    lossk<<<2048, 256, 0, stream>>>(emb, pos_part, neg_part, bsum);
    fin<<<1, 256, 0, stream>>>(bsum, out);
}

// Round 3
// 97.698 us; speedup vs baseline: 1.5750x; 1.5750x over previous
//
#include <hip/hip_runtime.h>
#include <stdint.h>

#define NROWS 8192
#define DIM 128
#define ROWB 256       // bytes per e16 row
#define NIBLK 32       // i-blocks of 256 rows
#define NCHUNK 32      // j-chunks of 256 cols
#define MARGIN 0.5f

typedef short short8 __attribute__((ext_vector_type(8)));   // 8 bf16 (4 VGPRs)
typedef float f32x4 __attribute__((ext_vector_type(4)));
typedef int   int4v __attribute__((ext_vector_type(4)));

#define GLDS16(g, l) __builtin_amdgcn_global_load_lds( \
    (const __attribute__((address_space(1))) unsigned int*)(g), \
    (__attribute__((address_space(3))) unsigned int*)(l), 16, 0, 0)

static __device__ __forceinline__ unsigned short f2bf(float f) {
    union { float f; unsigned u; } x; x.f = f;
    unsigned u = x.u;
    return (unsigned short)((u + 0x7FFFu + ((u >> 16) & 1u)) >> 16);  // RNE
}

// ---------------------------------------------------------------------------
// prep: bf16 copy of embeds, c_j = sq_j + 512 (f32 exact).
// ---------------------------------------------------------------------------
__global__ __launch_bounds__(256) void prep(const float* __restrict__ emb,
                                            unsigned short* __restrict__ e16,
                                            float* __restrict__ cbuf) {
    const int lane = threadIdx.x & 63;
    const int row = blockIdx.x * 4 + (threadIdx.x >> 6);
    const float2 v = reinterpret_cast<const float2*>(emb + row * DIM)[lane];
    float sq = v.x * v.x + v.y * v.y;
#pragma unroll
    for (int m = 1; m < 64; m <<= 1) sq += __shfl_xor(sq, m, 64);
    const unsigned pack = ((unsigned)f2bf(v.y) << 16) | (unsigned)f2bf(v.x);
    *reinterpret_cast<unsigned*>(e16 + row * DIM + lane * 2) = pack;
    if (lane == 0) cbuf[row] = sq + 512.0f;
}

// ---------------------------------------------------------------------------
// mine: fused Gram-GEMM + batch-hard mining, LDS-staged j-tiles.
// Grid: 32 i-blocks (256 rows) x 32 j-chunks (256 cols) = 1024 blocks.
// Block: 4 waves; wave owns 4 i-tiles of 16 (bfrag in regs all kernel).
// j-chunk processed in 4 stages of 64 j; each stage's 16KB tile staged into
// LDS once per block via global_load_lds (linear dest), double-buffered.
// Swizzle (both-sides): 16B-chunk index c ^= (row & 15) on the global SOURCE
// and on the ds_read address -> 2-way banks (free) instead of 16-way.
// Accumulator init = -c_j/2 so final s = dot - c_j/2 < 0:
//   hardest positive = max d2 -> MAX u32 bits of s
//   hardest negative = min d2 -> MIN u32 bits of s
// Candidate = (s_bits & ~8191) | j; sentinels 0 / 0xFFFFFFFF.
// ---------------------------------------------------------------------------
__global__ __launch_bounds__(256) void mine(const unsigned short* __restrict__ e16,
                                            const float* __restrict__ cbuf,
                                            const int* __restrict__ labels,
                                            unsigned* __restrict__ pos_part,
                                            unsigned* __restrict__ neg_part) {
    __shared__ char smem[2][16384];
    const int tid  = threadIdx.x;
    const int wave = tid >> 6;
    const int lane = tid & 63;
    const int l15  = lane & 15;
    const int lhi  = lane >> 4;
    const int iblk = blockIdx.x & (NIBLK - 1);
    const int cblk = blockIdx.x / NIBLK;
    const int ibase = iblk * 256 + wave * 64;
    const char* e8 = (const char*)e16;
    const int jcbase = cblk * 256;

    // Prologue stage of j-tile 0 (issued first so it overlaps bfrag loads).
    {
        const char* gs = e8 + (size_t)(jcbase + wave * 16) * ROWB;
        char* lb = &smem[0][wave * 4096];
#pragma unroll
        for (int q = 0; q < 4; ++q) {
            const int r16 = q * 4 + lhi;             // row within wave's 16
            const int ch  = l15 ^ r16;               // pre-swizzled source chunk
            GLDS16(gs + r16 * ROWB + ch * 16, lb + q * 1024);
        }
    }

    // B operand (i side): registers for the whole kernel.
    short8 bfrag[4][4];
    int labi[4];
#pragma unroll
    for (int it = 0; it < 4; ++it) {
        const int row = ibase + it * 16 + l15;
#pragma unroll
        for (int ks = 0; ks < 4; ++ks)
            bfrag[it][ks] = *reinterpret_cast<const short8*>(e8 + (size_t)row * ROWB + ks * 64 + lhi * 16);
        labi[it] = labels[row];
    }

    unsigned bp[4] = {0u, 0u, 0u, 0u};
    unsigned bn[4] = {0xFFFFFFFFu, 0xFFFFFFFFu, 0xFFFFFFFFu, 0xFFFFFFFFu};

    __syncthreads();   // prologue tile landed (barrier drains vmcnt)

#pragma unroll
    for (int st = 0; st < 4; ++st) {
        if (st < 3) {  // issue next-tile prefetch before compute
            const char* gs = e8 + (size_t)(jcbase + (st + 1) * 64 + wave * 16) * ROWB;
            char* lb = &smem[(st + 1) & 1][wave * 4096];
#pragma unroll
            for (int q = 0; q < 4; ++q) {
                const int r16 = q * 4 + lhi;
                const int ch  = l15 ^ r16;
                GLDS16(gs + r16 * ROWB + ch * 16, lb + q * 1024);
            }
        }
        const char* buf = smem[st & 1];
#pragma unroll
        for (int sub = 0; sub < 4; ++sub) {
            const int jb = jcbase + st * 64 + sub * 16;
            const int4v labj = *reinterpret_cast<const int4v*>(labels + jb + lhi * 4);
            const f32x4 c4   = *reinterpret_cast<const f32x4*>(cbuf + jb + lhi * 4);
            const f32x4 cinit = c4 * -0.5f;

            short8 af[4];
#pragma unroll
            for (int ks = 0; ks < 4; ++ks)
                af[ks] = *reinterpret_cast<const short8*>(
                    buf + (sub * 16 + l15) * ROWB + ((ks * 4 + lhi) ^ l15) * 16);

            f32x4 acc[4];
#pragma unroll
            for (int it = 0; it < 4; ++it)
                acc[it] = __builtin_amdgcn_mfma_f32_16x16x32_bf16(af[0], bfrag[it][0], cinit, 0, 0, 0);
#pragma unroll
            for (int ks = 1; ks < 4; ++ks)
#pragma unroll
                for (int it = 0; it < 4; ++it)
                    acc[it] = __builtin_amdgcn_mfma_f32_16x16x32_bf16(af[ks], bfrag[it][ks], acc[it], 0, 0, 0);

            const int j0 = jb + lhi * 4;
#pragma unroll
            for (int it = 0; it < 4; ++it) {
#pragma unroll
                for (int r = 0; r < 4; ++r) {
                    union { float f; unsigned u; } cv; cv.f = acc[it][r];
                    const unsigned cand = (cv.u & 0xFFFFE000u) | (unsigned)(j0 + r);
                    const bool eq = (labj[r] == labi[it]);
                    const unsigned psel = eq ? cand : 0u;
                    const unsigned nsel = eq ? 0xFFFFFFFFu : cand;
                    bp[it] = bp[it] > psel ? bp[it] : psel;
                    bn[it] = bn[it] < nsel ? bn[it] : nsel;
                }
            }
        }
        __syncthreads();   // drains prefetch (vmcnt) + protects buf reuse
    }

    // cross-lane: lanes {l, l^16, l^32, l^48} share the same i
#pragma unroll
    for (int it = 0; it < 4; ++it) {
        unsigned p = bp[it], n = bn[it];
        unsigned o;
        o = (unsigned)__shfl_xor((int)p, 16, 64); p = p > o ? p : o;
        o = (unsigned)__shfl_xor((int)p, 32, 64); p = p > o ? p : o;
        o = (unsigned)__shfl_xor((int)n, 16, 64); n = n < o ? n : o;
        o = (unsigned)__shfl_xor((int)n, 32, 64); n = n < o ? n : o;
        if (lane < 16) {
            pos_part[cblk * NROWS + ibase + it * 16 + lane] = p;
            neg_part[cblk * NROWS + ibase + it * 16 + lane] = n;
        }
    }
}

// ---------------------------------------------------------------------------
// lossk: one row per wave. Lanes 0-31 carry pos partials, 32-63 carry ~neg
// (complement turns min into max -> ONE packed butterfly). Exact f32 ap/an.
// ---------------------------------------------------------------------------
__global__ __launch_bounds__(256) void lossk(const float* __restrict__ emb,
                                             const unsigned* __restrict__ pos_part,
                                             const unsigned* __restrict__ neg_part,
                                             float* __restrict__ bsum) {
    __shared__ float wsum[4];
    const int tid = threadIdx.x, lane = tid & 63, wave = tid >> 6;
    const int i = blockIdx.x * 4 + wave;          // 0..8191
    const int c = lane & 31;
    unsigned v = (lane < 32) ? pos_part[c * NROWS + i] : ~neg_part[c * NROWS + i];
#pragma unroll
    for (int m = 1; m < 32; m <<= 1) {
        const unsigned o = (unsigned)__shfl_xor((int)v, m, 64);
        v = v > o ? v : o;
    }
    const unsigned o32 = (unsigned)__shfl_xor((int)v, 32, 64);
    const unsigned pmax = (lane < 32) ? v : o32;
    const unsigned nmin = ~((lane < 32) ? o32 : v);
    const int jp = (int)(pmax & 8191u);
    const int jn = (int)(nmin & 8191u);
    const float2 a = reinterpret_cast<const float2*>(emb + (size_t)i  * DIM)[lane];
    const float2 b = reinterpret_cast<const float2*>(emb + (size_t)jp * DIM)[lane];
    const float2 cc = reinterpret_cast<const float2*>(emb + (size_t)jn * DIM)[lane];
    float dx = a.x - b.x, dy = a.y - b.y;
    const float ap = dx * dx + dy * dy;
    dx = a.x - cc.x; dy = a.y - cc.y;
    const float an = dx * dx + dy * dy;
    float s = ap - an;
#pragma unroll
    for (int m = 1; m < 64; m <<= 1) s += __shfl_xor(s, m, 64);
    if (lane == 0) wsum[wave] = fmaxf(s + MARGIN, 0.f);
    __syncthreads();
    if (tid == 0) bsum[blockIdx.x] = wsum[0] + wsum[1] + wsum[2] + wsum[3];
}

// ---------------------------------------------------------------------------
// fin: reduce 2048 block sums -> mean. One block.
// ---------------------------------------------------------------------------
__global__ __launch_bounds__(256) void fin(const float* __restrict__ bsum,
                                           float* __restrict__ out) {
    __shared__ float wsum[4];
    const int tid = threadIdx.x, lane = tid & 63, wave = tid >> 6;
    float s = 0.f;
#pragma unroll
    for (int k = 0; k < 8; ++k) s += bsum[tid + k * 256];
#pragma unroll
    for (int m = 1; m < 64; m <<= 1) s += __shfl_xor(s, m, 64);
    if (lane == 0) wsum[wave] = s;
    __syncthreads();
    if (tid == 0) out[0] = (wsum[0] + wsum[1] + wsum[2] + wsum[3]) * (1.0f / (float)NROWS);
}

// ---------------------------------------------------------------------------
extern "C" void kernel_launch(void* const* d_in, const int* in_sizes, int n_in,
                              void* d_out, int out_size, void* d_ws, size_t ws_size,
                              hipStream_t stream) {
    const float* emb   = (const float*)d_in[0];
    const int* labels  = (const int*)d_in[1];
    float* out = (float*)d_out;
    char* ws = (char*)d_ws;

    unsigned short* e16 = (unsigned short*)ws;                         // 2 MB
    float* cbuf         = (float*)(ws + (size_t)2097152);              // 32 KB
    unsigned* pos_part  = (unsigned*)(ws + (size_t)2097152 + 32768);   // 1 MB
    unsigned* neg_part  = pos_part + (size_t)NCHUNK * NROWS;           // 1 MB
    float* bsum         = (float*)(neg_part + (size_t)NCHUNK * NROWS); // 8 KB

    prep<<<2048, 256, 0, stream>>>(emb, e16, cbuf);
    mine<<<NIBLK * NCHUNK, 256, 0, stream>>>(e16, cbuf, labels, pos_part, neg_part);
    lossk<<<2048, 256, 0, stream>>>(emb, pos_part, neg_part, bsum);
    fin<<<1, 256, 0, stream>>>(bsum, out);
}